// Round 8
// baseline (111.301 us; speedup 1.0000x reference)
//
#include <hip/hip_runtime.h>
#include <hip/hip_fp16.h>
#include <math.h>

// CTC loss forward, SINGLE fused kernel v10: v9 + producer cross-chunk
// LOAD PREFETCH (depth 1) + DPP row_bcast row-combine.
// One block of 1024 threads (16 waves) per batch element; B=256 = 256 CUs.
//
// v9 lesson: LDS-pipe diet (58->17 ops/chunk) was NULL -> prep not LDS-bound.
// All pipe estimates (VALU ~3us, trans ~3us, HBM ~5-10us) << observed prep.
// Untested on the lean body: LOAD LATENCY. v9 has no prefetch: each chunk is
// load(8x512B) -> wait(~700-1000cy; L2/L3 thrashed by the 268MB poison fills
// between iterations) -> compute(~600cy), strictly serial. v10 prefetches
// chunk k+NPS while computing k (clamp = reload-self, stays one basic block;
// +16 VGPR ~= 64 total, still 16 waves/CU). Row-combine: readlane x4 ->
// DPP row_bcast15/31 (lane63 = full sum, 1 readlane) - kills SALU trips.
// Consumers = v8/v9 verbatim (fwd-bwd split, cond renorm, f64 combiner).
// B=256, T=512, C=128 (blank=127), L=64, S=129.

constexpr int Cc = 128;
constexpr int Tt = 512;
constexpr int Ll = 64;
constexpr int NPS = 7;                      // producer waves per side
constexpr float INV_LN2 = 1.4426950408889634f;
constexpr float LN2_F   = 0.6931471805599453f;
constexpr float RENORM_THR = 16777216.0f;   // 2^24

__device__ __forceinline__ float fexp2(float x) { return __builtin_amdgcn_exp2f(x); }
__device__ __forceinline__ float flog2(float x) { return __builtin_amdgcn_logf(x); }

template<int CTRL, bool BC>
__device__ __forceinline__ float dppf(float old, float x) {
    return __int_as_float(__builtin_amdgcn_update_dpp(
        __float_as_int(old), __float_as_int(x), CTRL, 0xF, 0xF, BC));
}
// lane i <- lane i-1; lane 0 <- fill. (silicon-proven r3-r7)
__device__ __forceinline__ float wshr1(float x, float fill) { return dppf<0x138, false>(fill, x); }
// lane i <- lane i+1; lane 63 <- fill. (wave_shl1, mirror, proven v7)
__device__ __forceinline__ float wshl1(float x, float fill) { return dppf<0x130, false>(fill, x); }

__device__ __forceinline__ float rlf(float v, int lane) {
    return __int_as_float(__builtin_amdgcn_readlane(__float_as_int(v), lane));
}
// Row-local (16-lane) reduce; lanes 15/31/47/63 hold row results. (proven r6/r7)
__device__ __forceinline__ float rowsum(float e) {
    e += dppf<0x111, true>(0.f, e);
    e += dppf<0x112, true>(0.f, e);
    e += dppf<0x114, true>(0.f, e);
    e += dppf<0x118, true>(0.f, e);
    return e;
}
// full 64-lane sum landing in lane 63: rowsum + row_bcast15 + row_bcast31.
// After rowsum lanes 15/31/47/63 = s0..s3; bcast15 adds s0->lane31(,s1->47,
// s2->63); bcast31 adds (s0+s1)@31 -> lanes 32..63 => lane63 = s0+s1+s2+s3.
__device__ __forceinline__ float sum64_l63(float e) {
    e = rowsum(e);
    e += dppf<0x142, true>(0.f, e);   // row_bcast15
    e += dppf<0x143, true>(0.f, e);   // row_bcast31
    return e;
}
// all-lane wave max via butterfly shuffles (VGPR-only; used in rare renorm)
__device__ __forceinline__ float xmax64(float m) {
    m = fmaxf(m, __shfl_xor(m, 32, 64));
    m = fmaxf(m, __shfl_xor(m, 16, 64));
    m = fmaxf(m, __shfl_xor(m,  8, 64));
    m = fmaxf(m, __shfl_xor(m,  4, 64));
    m = fmaxf(m, __shfl_xor(m,  2, 64));
    m = fmaxf(m, __shfl_xor(m,  1, 64));
    return m;
}
__device__ __forceinline__ float bperm_f(int srclane, float v) {
    return __int_as_float(__builtin_amdgcn_ds_bpermute(srclane << 2, __float_as_int(v)));
}
// double butterfly-xor shuffle (two 32-bit halves)
__device__ __forceinline__ double shflx_d(double v, int mask) {
    const long long x = __double_as_longlong(v);
    int lo = (int)(x & 0xffffffffLL), hi = (int)(x >> 32);
    lo = __shfl_xor(lo, mask, 64);
    hi = __shfl_xor(hi, mask, 64);
    return __longlong_as_double(((long long)hi << 32) | (unsigned)(unsigned int)lo);
}

__device__ __forceinline__ void unpack8(uint4 raw, float (&dv)[8]) {
    const __half2 h0 = *reinterpret_cast<const __half2*>(&raw.x);
    const __half2 h1 = *reinterpret_cast<const __half2*>(&raw.y);
    const __half2 h2 = *reinterpret_cast<const __half2*>(&raw.z);
    const __half2 h3 = *reinterpret_cast<const __half2*>(&raw.w);
    dv[0] = __low2float(h0); dv[1] = __high2float(h0);
    dv[2] = __low2float(h1); dv[3] = __high2float(h1);
    dv[4] = __low2float(h2); dv[5] = __high2float(h2);
    dv[6] = __low2float(h3); dv[7] = __high2float(h3);
}

// ---- forward: 8 steps + CONDITIONAL renorm (v8-proven) ----
template<bool GUARD>
__device__ __forceinline__ void do_chunk(uint4 raw, int t0, int inlen, float skf,
                                         float& aO, float& aE, float& r0, float& Rtot)
{
    float dv[8]; unpack8(raw, dv);
    float sd[8];
#pragma unroll
    for (int j = 0; j < 8; ++j) sd[j] = skf * dv[j];
#pragma unroll
    for (int j = 0; j < 8; ++j) {
        if (!GUARD || (t0 + j < inlen)) {
            const float ad = aO * dv[j];
            const float pE = wshr1(aE, r0);
            const float pO = wshr1(aO, 0.0f);
            const float nO = fmaf(pE, dv[j], fmaf(pO, sd[j], ad));
            aE += aO;
            aO = nO;
        }
    }
    const float mx = fmaxf(fmaxf(aO, aE), r0);
    if (__any(mx >= RENORM_THR)) {
        const float M_ = xmax64(mx);
        int R_ = (int)(__float_as_uint(M_) >> 23) - 127;
        R_ = (R_ < 0) ? 0 : ((R_ > 126) ? 126 : R_);
        const float sc = __uint_as_float((unsigned)(127 - R_) << 23);
        aO = fminf(aO * sc, 4.0f);
        aE = fminf(aE * sc, 4.0f);
        r0 = fminf(r0 * sc, 4.0f);
        Rtot += (float)R_;
    }
}

// ---- backward (transpose), j descending, CONDITIONAL renorm (v8-proven) ----
template<bool GUARD>
__device__ __forceinline__ void do_chunk_bwd(uint4 raw, int t0, int inlen, float skfb,
                                             float& bO, float& bE, float& br, float& Rb,
                                             int l)
{
    float dv[8]; unpack8(raw, dv);
#pragma unroll
    for (int j = 7; j >= 0; --j) {
        if (!GUARD || (t0 + j < inlen)) {
            const float BOw = bO * dv[j];
            const float uO  = wshl1(BOw, 0.0f);
            const float t1  = bE + BOw;
            bE += uO;
            br += BOw;
            bO  = fmaf(skfb, uO, t1);
        }
    }
    const float brm = (l == 0) ? br : 0.0f;
    const float mx = fmaxf(fmaxf(bO, bE), brm);
    if (__any(mx >= RENORM_THR)) {
        const float M_ = xmax64(mx);
        int R_ = (int)(__float_as_uint(M_) >> 23) - 127;
        R_ = (R_ < 0) ? 0 : ((R_ > 126) ? 126 : R_);
        const float sc = __uint_as_float((unsigned)(127 - R_) << 23);
        bO = bO * sc;
        bE = bE * sc;
        br = br * sc;
        Rb += (float)R_;
    }
}

__global__ __launch_bounds__(1024, 1) void ctc_fused10_kernel(
    const int* __restrict__ y_true,      // [B, 64]
    const float* __restrict__ y_pred,    // [B, T, C]
    const int* __restrict__ in_len,      // [B]
    const int* __restrict__ lab_len,     // [B]
    float* __restrict__ out)             // [B]
{
    __shared__ __half w_lds[Tt / 8][64][8];   // [chunk][lane][t&7], 64 KB
    __shared__ float  ps[2 * NPS];            // per-producer blank partials (log2)
    __shared__ int    fctr[10], bctr[10];     // per-round counters (asc / desc)
    __shared__ int    bdone, pdone;
    __shared__ float  bstate[130];            // bE[64], bO[64], br0, Rb

    const int b   = blockIdx.x;
    const int tid = threadIdx.x;
    const int w   = tid >> 6;            // wave 0..15
    const int l   = tid & 63;

    if (tid < 10) { fctr[tid] = 0; bctr[tid] = 0; }
    if (tid == 0) { bdone = 0; pdone = 0; }
    __syncthreads();

    int inlen = in_len[b]; if (inlen < 1) inlen = 1; if (inlen > Tt) inlen = Tt;
    int LLv   = lab_len[b]; if (LLv < 1) LLv = 1; if (LLv > Ll) LLv = Ll;

    const int nct  = (inlen + 7) >> 3;   // total chunks (>= 32)
    const int nchf = nct >> 1;           // forward chunks [0, nchf)
    const int nchb = nct - nchf;         // backward chunks [nchf, nct), top-down

    const int lab = y_true[b * Ll + l] & 127;
    const float* rowbase = y_pred + (size_t)b * Tt * Cc;

    if (w >= 2) {
        // ------------- producers: one wave owns a whole chunk (8 rows) ----------
        // float2 layout: lane l holds classes 2l, 2l+1 of each row.
        const bool asc = (w < 9);
        const int pw    = asc ? (w - 2) : (w - 9);
        const int nside = asc ? nchf : nchb;
        const int glane = lab >> 1;          // fixed bpermute source lane
        const int lsel  = lab & 1;           // .x or .y at that lane
        const bool live = (l < LLv);         // dead lattice lanes -> w = 0
        int* ctr = asc ? fctr : bctr;

        float acc = 0.0f;

        if (pw < nside) {
            float2 cur[8], nxt[8];
            {   // preload first chunk
                const int r0 = (asc ? pw : (nct - 1 - pw)) * 8;
#pragma unroll
                for (int t = 0; t < 8; ++t)
                    cur[t] = ((const float2*)(rowbase + (size_t)(r0 + t) * Cc))[l];
            }
            for (int k = pw, idx = 0; k < nside; k += NPS, ++idx) {
                const int c = asc ? k : (nct - 1 - k);
                const int row0 = c * 8;
                // prefetch next chunk (clamp = reload-self; always legal, no branch)
                const int kn  = (k + NPS < nside) ? (k + NPS) : k;
                const int rn0 = (asc ? kn : (nct - 1 - kn)) * 8;
#pragma unroll
                for (int t = 0; t < 8; ++t)
                    nxt[t] = ((const float2*)(rowbase + (size_t)(rn0 + t) * Cc))[l];

                float prod = 1.0f, bsum = 0.0f;
                uint4 pk;

                // per-row worker: packed half bits of w for row row0+t.
                auto wbits = [&](int t) -> unsigned {
                    const float2 v = cur[t];
                    float e = fexp2(v.x * INV_LN2) + fexp2(v.y * INV_LN2);
                    e = sum64_l63(e);                  // lane 63 = full row sum
                    const float s  = rlf(e, 63);
                    const float bl = rlf(v.y, 63);     // class 127 logit
                    const bool ok = (row0 + t) < inlen;
                    prod *= ok ? s : 1.0f;
                    bsum += ok ? bl : 0.0f;
                    // label gather: 2 bpermutes with FIXED index
                    const float xa = bperm_f(glane, v.x);
                    const float xb = bperm_f(glane, v.y);
                    const float xl = lsel ? xb : xa;
                    float ww = fminf(fmaxf(fexp2((xl - bl) * INV_LN2), 6.1e-5f), 8192.0f);
                    ww = live ? ww : 0.0f;
                    return (unsigned)__half_as_ushort(__float2half(ww));
                };
                pk.x = wbits(0) | (wbits(1) << 16);
                pk.y = wbits(2) | (wbits(3) << 16);
                pk.z = wbits(4) | (wbits(5) << 16);
                pk.w = wbits(6) | (wbits(7) << 16);

                *(uint4*)&w_lds[c][l][0] = pk;         // ONE ds_write_b128/chunk
                asm volatile("s_waitcnt lgkmcnt(0)" ::: "memory");
                if (l == 0) atomicAdd(&ctr[idx], 1);
                acc = fmaf(bsum, INV_LN2, acc) - flog2(prod);
#pragma unroll
                for (int t = 0; t < 8; ++t) cur[t] = nxt[t];
            }
        }
        if (l == 0) ps[(asc ? 0 : NPS) + pw] = acc;
        asm volatile("s_waitcnt lgkmcnt(0)" ::: "memory");
        if (l == 0) atomicAdd(&pdone, 1);
        return;
    }

    // common to both consumers
    const int labp = __shfl_up(lab, 1, 64);
    const float skf = ((l >= 1) && (lab != labp)) ? 1.0f : 0.0f;

    if (w == 1) {
        // ---------------- backward consumer: beta recurrence, top-down ----------
        const float skfb = __shfl(skf, (l + 1) & 63, 64); // lane63: uO=0, value unused
        float bE = (l == LLv - 1) ? 1.0f : 0.0f;     // state 2*LLv (final blank)
        float bO = bE;                               // state 2*LLv-1 (final label)
        float br = 0.0f, Rb = 0.0f;

        volatile int* vd = bctr;
        int readyd = 0, rrd = 0;
        auto wait_d = [&](int cb) {                  // chunk cb ready (top-down count)
            const int needcnt = nct - cb;
            while (readyd < needcnt) {
                const int rem  = nchb - rrd * NPS;
                const int need = rem < NPS ? rem : NPS;
                if (vd[rrd] >= need) { readyd += need; ++rrd; }
                else __builtin_amdgcn_s_sleep(1);
            }
            asm volatile("" ::: "memory");
        };

        if (nchb > 0) {
            wait_d(nct - 1);
            uint4 A = *(const uint4*)&w_lds[nct - 1][l][0];
            for (int cb = nct - 1; cb >= nchf; --cb) {
                uint4 Bv = A;
                if (cb - 1 >= nchf) { wait_d(cb - 1); Bv = *(const uint4*)&w_lds[cb - 1][l][0]; }
                const int t0 = cb * 8;
                if (t0 + 8 <= inlen) do_chunk_bwd<false>(A, t0, inlen, skfb, bO, bE, br, Rb, l);
                else                 do_chunk_bwd<true >(A, t0, inlen, skfb, bO, bE, br, Rb, l);
                A = Bv;
            }
        }
        bstate[l]      = bE;
        bstate[64 + l] = bO;
        if (l == 0) { bstate[128] = br; bstate[129] = Rb; }
        asm volatile("s_waitcnt lgkmcnt(0)" ::: "memory");
        if (l == 0) atomicExch(&bdone, 1);
        return;
    }

    // ---------------- forward consumer: alpha recurrence, chunks [0,nchf) -------
    float aO = 0.0f, aE = 0.0f, r0 = 1.0f, Rf = 0.0f;

    volatile int* vf = fctr;
    int readyf = 0, rrf = 0;
    auto wait_f = [&](int cneed) {
        while (readyf <= cneed) {
            const int rem  = nchf - rrf * NPS;
            const int need = rem < NPS ? rem : NPS;
            if (vf[rrf] >= need) { readyf += need; ++rrf; }
            else __builtin_amdgcn_s_sleep(1);
        }
        asm volatile("" ::: "memory");
    };

    if (nchf > 0) {
        wait_f(0);
        uint4 A = *(const uint4*)&w_lds[0][l][0];
        for (int c = 0; c < nchf; ++c) {
            uint4 Bv = A;
            if (c + 1 < nchf) { wait_f(c + 1); Bv = *(const uint4*)&w_lds[c + 1][l][0]; }
            const int t0 = c * 8;
            if (t0 + 8 <= inlen) do_chunk<false>(A, t0, inlen, skf, aO, aE, r0, Rf);
            else                 do_chunk<true >(A, t0, inlen, skf, aO, aE, r0, Rf);
            A = Bv;
        }
    }

    // wait: all producers published ps; backward published bstate
    {
        volatile int* vp = &pdone;
        while (*vp < 2 * NPS) __builtin_amdgcn_s_sleep(1);
        volatile int* vbd = &bdone;
        while (*vbd == 0) __builtin_amdgcn_s_sleep(1);
        asm volatile("" ::: "memory");
    }

    float cum_b = 0.0f;
#pragma unroll
    for (int q = 0; q < 2 * NPS; ++q) cum_b += ps[q];

    // meeting-point dot in DOUBLE (exponent-safe): s = sum_s alpha(s)*beta(s)
    const float bEl = bstate[l], bOl = bstate[64 + l];
    const float br0 = bstate[128], Rb = bstate[129];
    double cd = (double)aE * (double)bEl + (double)aO * (double)bOl;
    if (l == 0) cd += (double)r0 * (double)br0;
#pragma unroll
    for (int mk = 1; mk < 64; mk <<= 1) cd += shflx_d(cd, mk);
    // log2 of the double via exponent extraction (cd uniform across lanes now)
    double sd_ = cd > 1e-300 ? cd : 1e-300;
    const long long u = __double_as_longlong(sd_);
    const int e2 = (int)((u >> 52) & 0x7ff) - 1023;
    const double mant = __longlong_as_double((u & 0xfffffffffffffLL) | 0x3ff0000000000000LL);
    const float l2s = (float)e2 + flog2((float)mant);
    if (l == 0)
        out[b] = -LN2_F * (l2s + Rf + Rb + cum_b);
}

extern "C" void kernel_launch(void* const* d_in, const int* in_sizes, int n_in,
                              void* d_out, int out_size, void* d_ws, size_t ws_size,
                              hipStream_t stream) {
    const int*   y_true  = (const int*)d_in[0];    // [256,64]
    const float* y_pred  = (const float*)d_in[1];  // [256,512,128]
    const int*   in_len  = (const int*)d_in[2];    // [256]
    const int*   lab_len = (const int*)d_in[3];    // [256]
    float*       out     = (float*)d_out;          // [256]
    (void)d_ws; (void)ws_size;

    ctc_fused10_kernel<<<256, 1024, 0, stream>>>(y_true, y_pred, in_len, lab_len, out);
}